// Round 10
// baseline (2000.266 us; speedup 1.0000x reference)
//
#include <hip/hip_runtime.h>
#include <cstddef>
#include <cstdint>

// DTYPE FACTS (r0–r5): inputs raw f32, outputs f32, expected side bf16-quantized.
// PRECISION MODEL (verified r6–r9, passed): reference = XLA f32, FMA chains:
//   d = fma(dz,dz, fma(dy,dy, dx*dx));  query n2/dot same shape.
// Selections (fps argmax, query top-k) keep these exact trees + ties->lowest idx.
// r9: max-pool before bn3 (monotone-affine, sign via gamma2); stats1 via Gram.
// r10: fps f32-butterfly + ballot index recovery; optional Y2 cache (ws_size-guarded)
//      so pass34 skips the conv1->conv2 recompute.

#define BB 16
#define NN 8192
#define DD 9
#define SS 1024
#define KK 32
#define M_COLS (BB*SS*KK)   // 524288
#define C1 64
#define C2 64
#define C3 128
#define NBKT 64
#define NG 54               // 9 first moments + 45 packed second moments

// ---------------- ws layout (BYTES) ----------------
#define WSB_IDX   0                          // u16 idx, M_COLS*2 = 1048576 B
#define WSB_STATS (WSB_IDX + M_COLS*2)       // 32768 floats
#define WSB_AFF   (WSB_STATS + 32768*4)      // 512 floats (sc1|sh1|sc2|sh2|sc3|sh3)
#define WSB_WT    (WSB_AFF + 512*4)          // 12864 floats (w0t | w1t | w2t)
#define WSB_END   (WSB_WT + 12864*4)
#define WSB_Y2    ((WSB_END + 255) & ~255)   // optional conv2 cache, C2*M_COLS*4 = 134 MB
// float offsets inside stats region:
#define PG1 0
#define PS2 (2*NBKT*C1)
#define PQ2 (3*NBKT*C1)
#define PS3 (4*NBKT*C1)
#define PQ3 (PS3 + NBKT*C3)

// ==================== FPS ====================
#define FPS_T   512
#define FPS_PPT (NN/FPS_T)   // 16
#define FPS_W   (FPS_T/64)   // 8

__global__ __launch_bounds__(FPS_T) void fps_kernel(const float* __restrict__ xyz,
                                                    float* __restrict__ out_newxyz) {
    __shared__ float sx[NN], sy[NN], sz[NN];
    __shared__ int   sfar[SS];
    __shared__ unsigned long long rp[2][FPS_W];
    const int b = blockIdx.x, tid = threadIdx.x;
    const int wave = tid >> 6, lane = tid & 63;
    const float* base = xyz + (size_t)b * NN * 3;
    for (int i = tid; i < NN; i += FPS_T) {
        sx[i] = base[i*3+0];
        sy[i] = base[i*3+1];
        sz[i] = base[i*3+2];
    }
    __syncthreads();
    float px[FPS_PPT], py[FPS_PPT], pz[FPS_PPT], dist[FPS_PPT];
#pragma unroll
    for (int m = 0; m < FPS_PPT; ++m) {
        int i = tid + m*FPS_T;
        px[m] = sx[i]; py[m] = sy[i]; pz[m] = sz[i];
        dist[m] = 1e10f;
    }
    if (tid == 0) sfar[0] = 0;
    float cx = sx[0], cy = sy[0], cz = sz[0];
    for (int it = 1; it < SS; ++it) {
        float lv = -1.0f; int lm = 0;
#pragma unroll
        for (int m = 0; m < FPS_PPT; ++m) {
            float dx = px[m]-cx, dy = py[m]-cy, dz = pz[m]-cz;
            float d  = fmaf(dz, dz, fmaf(dy, dy, dx*dx));   // exact ref tree
            float nd = fminf(dist[m], d);
            dist[m] = nd;
            if (nd > lv) { lv = nd; lm = m; }   // ascending idx per lane: > keeps lowest
        }
        int li = tid + lm*FPS_T;
        // value-only butterfly (f32), then index recovery
        float wv = lv;
#pragma unroll
        for (int msk = 1; msk < 64; msk <<= 1) wv = fmaxf(wv, __shfl_xor(wv, msk, 64));
        unsigned long long tied = __ballot(lv == wv);
        int wli;
        if ((tied & (tied - 1)) == 0) {            // unique max (wave-uniform branch)
            int src = __ffsll((unsigned long long)tied) - 1;
            wli = __shfl(li, src, 64);
        } else {                                   // rare: min index among tied lanes
            int cand = (lv == wv) ? li : 0x7FFFFFFF;
#pragma unroll
            for (int msk = 1; msk < 64; msk <<= 1) {
                int o = __shfl_xor(cand, msk, 64);
                cand = (o < cand) ? o : cand;
            }
            wli = cand;
        }
        unsigned long long pk = ((unsigned long long)__float_as_uint(wv) << 32)
                              | (unsigned int)(NN - 1 - wli);
        const int pb = it & 1;
        if (lane == 0) rp[pb][wave] = pk;
        __syncthreads();
        unsigned long long bp = rp[pb][0];
#pragma unroll
        for (int w = 1; w < FPS_W; ++w) {
            unsigned long long o = rp[pb][w];
            bp = (o > bp) ? o : bp;
        }
        int bi = NN - 1 - (int)(unsigned int)(bp & 0xFFFFFFFFull);
        if (tid == 0) sfar[it] = bi;
        cx = sx[bi]; cy = sy[bi]; cz = sz[bi];
    }
    __syncthreads();
    for (int s = tid; s < SS; s += FPS_T) {
        int nidx = sfar[s];
        out_newxyz[((size_t)b*SS + s)*3 + 0] = sx[nidx];
        out_newxyz[((size_t)b*SS + s)*3 + 1] = sy[nidx];
        out_newxyz[((size_t)b*SS + s)*3 + 2] = sz[nidx];
    }
}

// ==================== ball query: bitmap + recompute rescan + dual butterfly ====================
__device__ __forceinline__ unsigned fmap(float f) {
    unsigned u = __float_as_uint(f);
    return u ^ (unsigned)(((int)u >> 31) | 0x80000000);
}
#define PK_INF 0xFFFFFFFFFFFFFFFFull

__global__ __launch_bounds__(64) void query_kernel(const float* __restrict__ xyz,
                                                   const float* __restrict__ newxyz,
                                                   unsigned short* __restrict__ idx_out) {
    __shared__ unsigned bm[NN/32];
    const int blk  = blockIdx.x;     // b*1024 + s
    const int b    = blk >> 10;
    const int lane = threadIdx.x;
    for (int i = lane; i < NN/32; i += 64) bm[i] = 0;
    const float cx = newxyz[(size_t)blk*3+0];
    const float cy = newxyz[(size_t)blk*3+1];
    const float cz = newxyz[(size_t)blk*3+2];
    const float s2 = fmaf(cz, cz, fmaf(cy, cy, cx*cx));
    const float* xb = xyz + (size_t)b*NN*3;
    float lv = 3.0e38f; int li = 0;
    for (int m = 0; m < NN/64; ++m) {
        int j = lane + m*64;
        float x = xb[(size_t)j*3+0], y = xb[(size_t)j*3+1], z = xb[(size_t)j*3+2];
        float n2  = fmaf(z, z, fmaf(y, y, x*x));
        float dot = fmaf(cz, z, fmaf(cy, y, cx*x));
        float sq  = (s2 + n2) - 2.0f*dot;
        if (sq < lv) { lv = sq; li = j; }
    }
    __syncthreads();
    unsigned long long lpk = ((unsigned long long)fmap(lv) << 32) | (unsigned)li;
    unsigned long long g = lpk;
#pragma unroll
    for (int msk = 1; msk < 64; msk <<= 1) {
        unsigned long long o = __shfl_xor(g, msk, 64);
        g = (o < g) ? o : g;
    }
    const unsigned R2M = fmap(0.04f);
    int first_idx = 0, out_idx = 0;
    for (int k = 0; k < KK; ++k) {
        int wi = (int)(unsigned)(g & 0xFFFFFFFFull);
        unsigned wm = (unsigned)(g >> 32);
        if (k == 0) first_idx = wi;
        int keep = (wm > R2M) ? first_idx : wi;
        if (lane == k) out_idx = keep;
        int owner = wi & 63;
        if (lane == owner) bm[wi >> 5] |= (1u << (wi & 31));
        __syncthreads();
        int j0 = owner + ((2*lane) << 6);
        int j1 = j0 + 64;
        float x0 = xb[(size_t)j0*3+0], y0 = xb[(size_t)j0*3+1], z0 = xb[(size_t)j0*3+2];
        float x1 = xb[(size_t)j1*3+0], y1 = xb[(size_t)j1*3+1], z1 = xb[(size_t)j1*3+2];
        float sq0 = (s2 + fmaf(z0, z0, fmaf(y0, y0, x0*x0))) - 2.0f*fmaf(cz, z0, fmaf(cy, y0, cx*x0));
        float sq1 = (s2 + fmaf(z1, z1, fmaf(y1, y1, x1*x1))) - 2.0f*fmaf(cz, z1, fmaf(cy, y1, cx*x1));
        bool t0 = (bm[j0 >> 5] >> (j0 & 31)) & 1;
        bool t1 = (bm[j1 >> 5] >> (j1 & 31)) & 1;
        unsigned long long p0 = t0 ? PK_INF : (((unsigned long long)fmap(sq0) << 32) | (unsigned)j0);
        unsigned long long p1 = t1 ? PK_INF : (((unsigned long long)fmap(sq1) << 32) | (unsigned)j1);
        unsigned long long r = (p1 < p0) ? p1 : p0;
        unsigned long long c = (lane == owner) ? PK_INF : lpk;
        c = (r < c) ? r : c;
#pragma unroll
        for (int msk = 1; msk < 64; msk <<= 1) {
            unsigned long long ro = __shfl_xor(r, msk, 64);
            unsigned long long co = __shfl_xor(c, msk, 64);
            r = (ro < r) ? ro : r;
            c = (co < c) ? co : c;
        }
        if (lane == owner) lpk = r;
        g = c;
        __syncthreads();
    }
    if (lane < KK) idx_out[(size_t)blk*KK + lane] = (unsigned short)out_idx;
}

// ==================== transpose weights ====================
__global__ void transpose_w_kernel(const float* __restrict__ W0, const float* __restrict__ W1,
                                   const float* __restrict__ W2, float* __restrict__ w0t,
                                   float* __restrict__ w1t, float* __restrict__ w2t) {
    int t = blockIdx.x*256 + threadIdx.x;
    if (t < DD*C1)  { int c = t / C1, o = t % C1; w0t[t] = W0[o*DD + c]; }
    if (t < C1*C2)  { int c = t / C2, o = t % C2; w1t[t] = W1[o*C1 + c]; }
    if (t < C1*C3)  { int c = t / C3, o = t % C3; w2t[t] = W2[o*C1 + c]; }
}

// ==================== gram ====================
__global__ __launch_bounds__(256) void gram_kernel(const float* __restrict__ points,
                                                   const unsigned short* __restrict__ idxw,
                                                   float* __restrict__ pg) {
    __shared__ float sg[NG];
    const int tid = threadIdx.x, lane = tid & 63;
    float acc[NG];
#pragma unroll
    for (int t = 0; t < NG; ++t) acc[t] = 0.f;
#pragma unroll
    for (int i = 0; i < 4; ++i) {
        int col = blockIdx.x*1024 + i*256 + tid;
        int n = idxw[col];
        int b = col >> 15;
        const float* p = points + ((size_t)b*NN + n)*DD;
        float x[DD];
#pragma unroll
        for (int c = 0; c < DD; ++c) x[c] = p[c];
#pragma unroll
        for (int c = 0; c < DD; ++c) acc[c] += x[c];
        int t = DD;
#pragma unroll
        for (int c = 0; c < DD; ++c)
#pragma unroll
            for (int d = c; d < DD; ++d) { acc[t] = fmaf(x[c], x[d], acc[t]); ++t; }
    }
#pragma unroll
    for (int t = 0; t < NG; ++t) {
#pragma unroll
        for (int msk = 1; msk < 64; msk <<= 1) acc[t] += __shfl_xor(acc[t], msk, 64);
    }
    if (tid < NG) sg[tid] = 0.f;
    __syncthreads();
    if (lane == 0) {
#pragma unroll
        for (int t = 0; t < NG; ++t) atomicAdd(&sg[t], acc[t]);
    }
    __syncthreads();
    int bkt = blockIdx.x & (NBKT-1);
    if (tid < NG) atomicAdd(&pg[bkt*64 + tid], sg[tid]);
}

// ==================== affine1: stats1 closed-form from Gram ====================
__global__ void affine1_kernel(const float* __restrict__ pg,
                               const float* __restrict__ W0, const float* __restrict__ b0,
                               const float* __restrict__ gamma, const float* __restrict__ beta,
                               float* __restrict__ scale, float* __restrict__ shift) {
    __shared__ float sm[NG];
    int tid = threadIdx.x;
    if (tid < NG) {
        float s = 0.f;
        for (int b = 0; b < NBKT; ++b) s += pg[b*64 + tid];
        sm[tid] = s;
    }
    __syncthreads();
    if (tid < C1) {
        float w[DD];
#pragma unroll
        for (int i = 0; i < DD; ++i) w[i] = W0[tid*DD + i];
        float mv = 0.f;
#pragma unroll
        for (int i = 0; i < DD; ++i) mv = fmaf(w[i], sm[i], mv);
        float q = 0.f;
        int t = DD;
#pragma unroll
        for (int c = 0; c < DD; ++c)
#pragma unroll
            for (int d = c; d < DD; ++d) {
                float coef = w[c]*w[d];
                if (c != d) coef = coef + coef;
                q = fmaf(coef, sm[t], q); ++t;
            }
        float b0v = b0[tid];
        const float M = (float)M_COLS;
        float s_sum = mv + M*b0v;
        float s_sq  = q + 2.f*b0v*mv + M*b0v*b0v;
        const float invM = 1.0f / M;
        float mean = s_sum * invM;
        float var  = s_sq * invM - mean*mean;
        float sc   = gamma[tid] / sqrtf(var + 1e-5f);
        scale[tid] = sc;
        shift[tid] = beta[tid] - mean*sc;
    }
}

// ==================== stats helper ====================
__device__ __forceinline__ void stats_accumulate64(const float* acc,
                                                   float* __restrict__ g_sum,
                                                   float* __restrict__ g_sq) {
    __shared__ float s_sum[C1];
    __shared__ float s_sq[C1];
    int tid = threadIdx.x, lane = tid & 63;
    if (tid < C1) { s_sum[tid] = 0.f; s_sq[tid] = 0.f; }
    __syncthreads();
#pragma unroll
    for (int o = 0; o < C1; ++o) {
        float v = acc[o];
        float q = v*v;
#pragma unroll
        for (int msk = 1; msk < 64; msk <<= 1) {
            v += __shfl_xor(v, msk, 64);
            q += __shfl_xor(q, msk, 64);
        }
        if (lane == 0) { atomicAdd(&s_sum[o], v); atomicAdd(&s_sq[o], q); }
    }
    __syncthreads();
    if (tid < C1) { atomicAdd(&g_sum[tid], s_sum[tid]); atomicAdd(&g_sq[tid], s_sq[tid]); }
    __syncthreads();
}

// ==================== gather + conv1 ====================
__device__ __forceinline__ void gather_conv1(const float* __restrict__ points,
                                             const unsigned short* __restrict__ idxw,
                                             const float* __restrict__ w0t,
                                             const float* __restrict__ b0,
                                             int col, float (&a1)[C1]) {
    int n = idxw[col];
    int b = col >> 15;
    const float* p = points + ((size_t)b*NN + n)*DD;
    float x[DD];
#pragma unroll
    for (int c = 0; c < DD; ++c) x[c] = p[c];
#pragma unroll
    for (int o = 0; o < C1; ++o) a1[o] = b0[o];
#pragma unroll
    for (int c = 0; c < DD; ++c) {
        float xc = x[c];
#pragma unroll
        for (int o = 0; o < C1; ++o) a1[o] = fmaf(w0t[c*C1+o], xc, a1[o]);
    }
}

// ==================== conv2 from bn1(a1) ====================
__device__ __forceinline__ void conv2_from_a1(float (&a1)[C1],
                                              const float* __restrict__ sc1,
                                              const float* __restrict__ sh1,
                                              const float* __restrict__ w1t,
                                              const float* __restrict__ b1,
                                              float (&a2)[C2]) {
#pragma unroll
    for (int c = 0; c < C1; ++c) a1[c] = fmaxf(fmaf(a1[c], sc1[c], sh1[c]), 0.0f);
#pragma unroll
    for (int o = 0; o < C2; ++o) a2[o] = b1[o];
    for (int c = 0; c < C1; ++c) {
        float xc = a1[c];
#pragma unroll
        for (int o = 0; o < C2; ++o) a2[o] = fmaf(w1t[c*C2+o], xc, a2[o]);
    }
}

// ==================== affine (bucketed) ====================
__global__ void affine_kernel(const float* __restrict__ psum, const float* __restrict__ psq,
                              const float* __restrict__ gamma, const float* __restrict__ beta,
                              float* __restrict__ scale, float* __restrict__ shift, int nch) {
    int i = threadIdx.x;
    if (i < nch) {
        float s = 0.f, q = 0.f;
        for (int b = 0; b < NBKT; ++b) { s += psum[b*nch + i]; q += psq[b*nch + i]; }
        const float invM = 1.0f / (float)M_COLS;
        float mean = s * invM;
        float var  = q * invM - mean*mean;
        float sc   = gamma[i] / sqrtf(var + 1e-5f);
        scale[i] = sc;
        shift[i] = beta[i] - mean*sc;
    }
}

// ==================== pass2 (two variants: with/without Y2 store) ====================
template<bool STORE>
__device__ __forceinline__ void pass2_body(const float* __restrict__ points,
                                           const unsigned short* __restrict__ idxw,
                                           const float* __restrict__ w0t,
                                           const float* __restrict__ b0,
                                           const float* __restrict__ sc1,
                                           const float* __restrict__ sh1,
                                           const float* __restrict__ w1t,
                                           const float* __restrict__ b1,
                                           float* __restrict__ Y2,
                                           float* __restrict__ pstats) {
    int col = blockIdx.x*256 + threadIdx.x;
    int bkt = blockIdx.x & (NBKT-1);
    float a1[C1], a2[C2];
    gather_conv1(points, idxw, w0t, b0, col, a1);
    conv2_from_a1(a1, sc1, sh1, w1t, b1, a2);
    if (STORE) {
#pragma unroll
        for (int o = 0; o < C2; ++o) Y2[(size_t)o*M_COLS + col] = a2[o];
    }
    stats_accumulate64(a2, pstats + PS2 + bkt*C1, pstats + PQ2 + bkt*C1);
}

__global__ __launch_bounds__(256) void pass2_kernel(const float* __restrict__ points,
                                                    const unsigned short* __restrict__ idxw,
                                                    const float* __restrict__ w0t,
                                                    const float* __restrict__ b0,
                                                    const float* __restrict__ sc1,
                                                    const float* __restrict__ sh1,
                                                    const float* __restrict__ w1t,
                                                    const float* __restrict__ b1,
                                                    float* __restrict__ pstats) {
    pass2_body<false>(points, idxw, w0t, b0, sc1, sh1, w1t, b1, nullptr, pstats);
}

__global__ __launch_bounds__(256) void pass2_store_kernel(const float* __restrict__ points,
                                                          const unsigned short* __restrict__ idxw,
                                                          const float* __restrict__ w0t,
                                                          const float* __restrict__ b0,
                                                          const float* __restrict__ sc1,
                                                          const float* __restrict__ sh1,
                                                          const float* __restrict__ w1t,
                                                          const float* __restrict__ b1,
                                                          float* __restrict__ Y2,
                                                          float* __restrict__ pstats) {
    pass2_body<true>(points, idxw, w0t, b0, sc1, sh1, w1t, b1, Y2, pstats);
}

// ==================== pass34 core: bn2 -> conv3 -> pool + stats ====================
__device__ __forceinline__ void pass34_tail(float (&a2)[C2],
                                            const float* __restrict__ sc2,
                                            const float* __restrict__ sh2,
                                            const float* __restrict__ w2t,
                                            const float* __restrict__ b2,
                                            const float* __restrict__ gamma2,
                                            float* __restrict__ pool_out,
                                            float* __restrict__ pstats) {
#pragma unroll
    for (int c = 0; c < C2; ++c) a2[c] = fmaxf(fmaf(a2[c], sc2[c], sh2[c]), 0.0f);
    int col = blockIdx.x*256 + threadIdx.x;
    int bkt = blockIdx.x & (NBKT-1);
    int lane = threadIdx.x & 63;
    int bs = col >> 5;
#pragma unroll
    for (int h = 0; h < 2; ++h) {
        float acc[C1];
#pragma unroll
        for (int o = 0; o < C1; ++o) acc[o] = b2[h*C1+o];
        for (int c = 0; c < C2; ++c) {
            float xc = a2[c];
#pragma unroll
            for (int o = 0; o < C1; ++o) acc[o] = fmaf(w2t[c*C3 + h*C1 + o], xc, acc[o]);
        }
#pragma unroll
        for (int o = 0; o < C1; ++o) {
            bool pos = gamma2[h*C1+o] >= 0.f;
            float v = pos ? acc[o] : -acc[o];
#pragma unroll
            for (int msk = 1; msk < 32; msk <<= 1) v = fmaxf(v, __shfl_xor(v, msk, 64));
            if ((lane & 31) == 0) pool_out[(size_t)bs*C3 + h*C1 + o] = pos ? v : -v;
        }
        stats_accumulate64(acc, pstats + PS3 + bkt*C3 + h*C1, pstats + PQ3 + bkt*C3 + h*C1);
    }
}

__global__ __launch_bounds__(256) void pass34_kernel(const float* __restrict__ points,
                                                     const unsigned short* __restrict__ idxw,
                                                     const float* __restrict__ w0t,
                                                     const float* __restrict__ b0,
                                                     const float* __restrict__ sc1,
                                                     const float* __restrict__ sh1,
                                                     const float* __restrict__ w1t,
                                                     const float* __restrict__ b1,
                                                     const float* __restrict__ sc2,
                                                     const float* __restrict__ sh2,
                                                     const float* __restrict__ w2t,
                                                     const float* __restrict__ b2,
                                                     const float* __restrict__ gamma2,
                                                     float* __restrict__ pool_out,
                                                     float* __restrict__ pstats) {
    int col = blockIdx.x*256 + threadIdx.x;
    float a1[C1], a2[C2];
    gather_conv1(points, idxw, w0t, b0, col, a1);
    conv2_from_a1(a1, sc1, sh1, w1t, b1, a2);
    pass34_tail(a2, sc2, sh2, w2t, b2, gamma2, pool_out, pstats);
}

__global__ __launch_bounds__(256) void pass34_cached_kernel(const float* __restrict__ Y2,
                                                            const float* __restrict__ sc2,
                                                            const float* __restrict__ sh2,
                                                            const float* __restrict__ w2t,
                                                            const float* __restrict__ b2,
                                                            const float* __restrict__ gamma2,
                                                            float* __restrict__ pool_out,
                                                            float* __restrict__ pstats) {
    int col = blockIdx.x*256 + threadIdx.x;
    float a2[C2];
#pragma unroll
    for (int o = 0; o < C2; ++o) a2[o] = Y2[(size_t)o*M_COLS + col];
    pass34_tail(a2, sc2, sh2, w2t, b2, gamma2, pool_out, pstats);
}

// ==================== epilogue: bn3 + relu ====================
__global__ __launch_bounds__(256) void bn3relu_kernel(float* __restrict__ pool,
                                                      const float* __restrict__ sc3,
                                                      const float* __restrict__ sh3) {
    int e = blockIdx.x*256 + threadIdx.x;
    int ch = e & (C3-1);
    float v = pool[e];
    pool[e] = fmaxf(fmaf(v, sc3[ch], sh3[ch]), 0.0f);
}

extern "C" void kernel_launch(void* const* d_in, const int* in_sizes, int n_in,
                              void* d_out, int out_size, void* d_ws, size_t ws_size,
                              hipStream_t stream) {
    const float* xyz    = (const float*)d_in[0];
    const float* points = (const float*)d_in[1];
    const float* W0     = (const float*)d_in[2];
    const float* b0     = (const float*)d_in[3];
    const float* gamma0 = (const float*)d_in[4];
    const float* beta0  = (const float*)d_in[5];
    const float* W1     = (const float*)d_in[6];
    const float* b1     = (const float*)d_in[7];
    const float* gamma1 = (const float*)d_in[8];
    const float* beta1  = (const float*)d_in[9];
    const float* W2     = (const float*)d_in[10];
    const float* b2     = (const float*)d_in[11];
    const float* gamma2 = (const float*)d_in[12];
    const float* beta2  = (const float*)d_in[13];

    char* wsb = (char*)d_ws;
    unsigned short* idxw = (unsigned short*)(wsb + WSB_IDX);
    float* pstats = (float*)(wsb + WSB_STATS);
    float* aff = (float*)(wsb + WSB_AFF);
    float* sc1 = aff,       *sh1 = aff + 64;
    float* sc2 = aff + 128, *sh2 = aff + 192;
    float* sc3 = aff + 256, *sh3 = aff + 384;
    float* wT  = (float*)(wsb + WSB_WT);
    float* w0t = wT, *w1t = wT + DD*C1, *w2t = wT + DD*C1 + C1*C2;
    float* Y2  = (float*)(wsb + WSB_Y2);
    const bool use_y2 = ws_size >= (size_t)WSB_Y2 + (size_t)C2 * M_COLS * 4;

    float* out_newxyz = (float*)d_out;
    float* out_feat   = (float*)d_out + (size_t)BB*SS*3;

    hipMemsetAsync(pstats, 0, 32768*sizeof(float), stream);
    fps_kernel<<<dim3(BB), dim3(FPS_T), 0, stream>>>(xyz, out_newxyz);
    transpose_w_kernel<<<dim3(32), dim3(256), 0, stream>>>(W0, W1, W2, w0t, w1t, w2t);
    query_kernel<<<dim3(BB*SS), dim3(64), 0, stream>>>(xyz, out_newxyz, idxw);
    gram_kernel<<<dim3(M_COLS/1024), dim3(256), 0, stream>>>(points, idxw, pstats + PG1);
    affine1_kernel<<<dim3(1), dim3(64), 0, stream>>>(pstats + PG1, W0, b0, gamma0, beta0, sc1, sh1);
    if (use_y2) {
        pass2_store_kernel<<<dim3(M_COLS/256), dim3(256), 0, stream>>>(points, idxw, w0t, b0, sc1, sh1, w1t, b1, Y2, pstats);
        affine_kernel<<<dim3(1), dim3(128), 0, stream>>>(pstats + PS2, pstats + PQ2, gamma1, beta1, sc2, sh2, C2);
        pass34_cached_kernel<<<dim3(M_COLS/256), dim3(256), 0, stream>>>(Y2, sc2, sh2, w2t, b2, gamma2, out_feat, pstats);
    } else {
        pass2_kernel<<<dim3(M_COLS/256), dim3(256), 0, stream>>>(points, idxw, w0t, b0, sc1, sh1, w1t, b1, pstats);
        affine_kernel<<<dim3(1), dim3(128), 0, stream>>>(pstats + PS2, pstats + PQ2, gamma1, beta1, sc2, sh2, C2);
        pass34_kernel<<<dim3(M_COLS/256), dim3(256), 0, stream>>>(points, idxw, w0t, b0, sc1, sh1, w1t, b1, sc2, sh2, w2t, b2, gamma2, out_feat, pstats);
    }
    affine_kernel<<<dim3(1), dim3(128), 0, stream>>>(pstats + PS3, pstats + PQ3, gamma2, beta2, sc3, sh3, C3);
    bn3relu_kernel<<<dim3((BB*SS*C3)/256), dim3(256), 0, stream>>>(out_feat, sc3, sh3);
}

// Round 11
// 1683.322 us; speedup vs baseline: 1.1883x; 1.1883x over previous
//
#include <hip/hip_runtime.h>
#include <cstddef>
#include <cstdint>

// DTYPE FACTS (r0–r5): inputs raw f32, outputs f32, expected side bf16-quantized.
// PRECISION MODEL (verified r6–r10, passed): reference = XLA f32, FMA chains:
//   d = fma(dz,dz, fma(dy,dy, dx*dx));  query n2/dot same shape.
// Selections (fps argmax, query top-k) keep these exact trees + ties->lowest idx.
// r9: max-pool before bn3 (monotone-affine, sign via gamma2); stats1 via Gram.
// r10 lesson: ballot+branch AFTER a value butterfly adds serial latency — regressed.
// r11: DPP wave reduction (row_shr + row_bcast + readlane, pure VALU ~4cyc/step)
//      replaces the ds_bpermute-based __shfl_xor butterfly in fps; branch-free
//      index recovery via predicated second DPP pass (complement max = min idx).

#define BB 16
#define NN 8192
#define DD 9
#define SS 1024
#define KK 32
#define M_COLS (BB*SS*KK)   // 524288
#define C1 64
#define C2 64
#define C3 128
#define NBKT 64
#define NG 54               // 9 first moments + 45 packed second moments

// ---------------- ws layout (BYTES) ----------------
#define WSB_IDX   0                          // u16 idx, M_COLS*2 = 1048576 B
#define WSB_STATS (WSB_IDX + M_COLS*2)       // 32768 floats
#define WSB_AFF   (WSB_STATS + 32768*4)      // 512 floats (sc1|sh1|sc2|sh2|sc3|sh3)
#define WSB_WT    (WSB_AFF + 512*4)          // 12864 floats (w0t | w1t | w2t)
#define WSB_END   (WSB_WT + 12864*4)
#define WSB_Y2    ((WSB_END + 255) & ~255)   // optional conv2 cache, C2*M_COLS*4 = 134 MB
// float offsets inside stats region:
#define PG1 0
#define PS2 (2*NBKT*C1)
#define PQ2 (3*NBKT*C1)
#define PS3 (4*NBKT*C1)
#define PQ3 (PS3 + NBKT*C3)

// ==================== DPP wave-64 u32 max (result wave-uniform) ====================
// row_shr:1/2/4/8 build per-row(16) max into lane 15 of each row; row_bcast15 and
// row_bcast31 fold rows; lane 63 holds the full max; readlane broadcasts via SGPR.
__device__ __forceinline__ unsigned wave_umax_dpp(unsigned v) {
    int x = (int)v, t;
    t = __builtin_amdgcn_update_dpp(x, x, 0x111, 0xf, 0xf, false);   // row_shr:1
    x = ((unsigned)t > (unsigned)x) ? t : x;
    t = __builtin_amdgcn_update_dpp(x, x, 0x112, 0xf, 0xf, false);   // row_shr:2
    x = ((unsigned)t > (unsigned)x) ? t : x;
    t = __builtin_amdgcn_update_dpp(x, x, 0x114, 0xf, 0xf, false);   // row_shr:4
    x = ((unsigned)t > (unsigned)x) ? t : x;
    t = __builtin_amdgcn_update_dpp(x, x, 0x118, 0xf, 0xf, false);   // row_shr:8
    x = ((unsigned)t > (unsigned)x) ? t : x;
    t = __builtin_amdgcn_update_dpp(x, x, 0x142, 0xf, 0xf, false);   // row_bcast:15
    x = ((unsigned)t > (unsigned)x) ? t : x;
    t = __builtin_amdgcn_update_dpp(x, x, 0x143, 0xf, 0xf, false);   // row_bcast:31
    x = ((unsigned)t > (unsigned)x) ? t : x;
    return (unsigned)__builtin_amdgcn_readlane(x, 63);
}

// ==================== FPS ====================
#define FPS_T   512
#define FPS_PPT (NN/FPS_T)   // 16
#define FPS_W   (FPS_T/64)   // 8

__global__ __launch_bounds__(FPS_T) void fps_kernel(const float* __restrict__ xyz,
                                                    float* __restrict__ out_newxyz) {
    __shared__ float sx[NN], sy[NN], sz[NN];
    __shared__ int   sfar[SS];
    __shared__ unsigned long long rp[2][FPS_W];
    const int b = blockIdx.x, tid = threadIdx.x;
    const int wave = tid >> 6, lane = tid & 63;
    const float* base = xyz + (size_t)b * NN * 3;
    for (int i = tid; i < NN; i += FPS_T) {
        sx[i] = base[i*3+0];
        sy[i] = base[i*3+1];
        sz[i] = base[i*3+2];
    }
    __syncthreads();
    float px[FPS_PPT], py[FPS_PPT], pz[FPS_PPT], dist[FPS_PPT];
#pragma unroll
    for (int m = 0; m < FPS_PPT; ++m) {
        int i = tid + m*FPS_T;
        px[m] = sx[i]; py[m] = sy[i]; pz[m] = sz[i];
        dist[m] = 1e10f;
    }
    if (tid == 0) sfar[0] = 0;
    float cx = sx[0], cy = sy[0], cz = sz[0];
    for (int it = 1; it < SS; ++it) {
        float lv = -1.0f; int lm = 0;
#pragma unroll
        for (int m = 0; m < FPS_PPT; ++m) {
            float dx = px[m]-cx, dy = py[m]-cy, dz = pz[m]-cz;
            float d  = fmaf(dz, dz, fmaf(dy, dy, dx*dx));   // exact ref tree
            float nd = fminf(dist[m], d);
            dist[m] = nd;
            if (nd > lv) { lv = nd; lm = m; }   // ascending idx per lane: > keeps lowest
        }
        int li = tid + lm*FPS_T;
        // lv >= 0 after m=0, so f32 order == u32 order on the raw bits.
        unsigned uv  = __float_as_uint(lv);
        unsigned wvu = wave_umax_dpp(uv);                       // wave max value
        unsigned ci  = (uv == wvu) ? (unsigned)(NN - 1 - li) : 0u;
        unsigned cm  = wave_umax_dpp(ci);                       // max complement = min idx
        const int pb = it & 1;
        if (lane == 0) rp[pb][wave] = ((unsigned long long)wvu << 32) | cm;
        __syncthreads();
        unsigned long long bp = rp[pb][0];
#pragma unroll
        for (int w = 1; w < FPS_W; ++w) {
            unsigned long long o = rp[pb][w];
            bp = (o > bp) ? o : bp;
        }
        int bi = NN - 1 - (int)(unsigned int)(bp & 0xFFFFFFFFull);
        if (tid == 0) sfar[it] = bi;
        cx = sx[bi]; cy = sy[bi]; cz = sz[bi];
    }
    __syncthreads();
    for (int s = tid; s < SS; s += FPS_T) {
        int nidx = sfar[s];
        out_newxyz[((size_t)b*SS + s)*3 + 0] = sx[nidx];
        out_newxyz[((size_t)b*SS + s)*3 + 1] = sy[nidx];
        out_newxyz[((size_t)b*SS + s)*3 + 2] = sz[nidx];
    }
}

// ==================== ball query: bitmap + recompute rescan + dual butterfly ====================
__device__ __forceinline__ unsigned fmap(float f) {
    unsigned u = __float_as_uint(f);
    return u ^ (unsigned)(((int)u >> 31) | 0x80000000);
}
#define PK_INF 0xFFFFFFFFFFFFFFFFull

__global__ __launch_bounds__(64) void query_kernel(const float* __restrict__ xyz,
                                                   const float* __restrict__ newxyz,
                                                   unsigned short* __restrict__ idx_out) {
    __shared__ unsigned bm[NN/32];
    const int blk  = blockIdx.x;     // b*1024 + s
    const int b    = blk >> 10;
    const int lane = threadIdx.x;
    for (int i = lane; i < NN/32; i += 64) bm[i] = 0;
    const float cx = newxyz[(size_t)blk*3+0];
    const float cy = newxyz[(size_t)blk*3+1];
    const float cz = newxyz[(size_t)blk*3+2];
    const float s2 = fmaf(cz, cz, fmaf(cy, cy, cx*cx));
    const float* xb = xyz + (size_t)b*NN*3;
    float lv = 3.0e38f; int li = 0;
    for (int m = 0; m < NN/64; ++m) {
        int j = lane + m*64;
        float x = xb[(size_t)j*3+0], y = xb[(size_t)j*3+1], z = xb[(size_t)j*3+2];
        float n2  = fmaf(z, z, fmaf(y, y, x*x));
        float dot = fmaf(cz, z, fmaf(cy, y, cx*x));
        float sq  = (s2 + n2) - 2.0f*dot;
        if (sq < lv) { lv = sq; li = j; }
    }
    __syncthreads();
    unsigned long long lpk = ((unsigned long long)fmap(lv) << 32) | (unsigned)li;
    unsigned long long g = lpk;
#pragma unroll
    for (int msk = 1; msk < 64; msk <<= 1) {
        unsigned long long o = __shfl_xor(g, msk, 64);
        g = (o < g) ? o : g;
    }
    const unsigned R2M = fmap(0.04f);
    int first_idx = 0, out_idx = 0;
    for (int k = 0; k < KK; ++k) {
        int wi = (int)(unsigned)(g & 0xFFFFFFFFull);
        unsigned wm = (unsigned)(g >> 32);
        if (k == 0) first_idx = wi;
        int keep = (wm > R2M) ? first_idx : wi;
        if (lane == k) out_idx = keep;
        int owner = wi & 63;
        if (lane == owner) bm[wi >> 5] |= (1u << (wi & 31));
        __syncthreads();
        int j0 = owner + ((2*lane) << 6);
        int j1 = j0 + 64;
        float x0 = xb[(size_t)j0*3+0], y0 = xb[(size_t)j0*3+1], z0 = xb[(size_t)j0*3+2];
        float x1 = xb[(size_t)j1*3+0], y1 = xb[(size_t)j1*3+1], z1 = xb[(size_t)j1*3+2];
        float sq0 = (s2 + fmaf(z0, z0, fmaf(y0, y0, x0*x0))) - 2.0f*fmaf(cz, z0, fmaf(cy, y0, cx*x0));
        float sq1 = (s2 + fmaf(z1, z1, fmaf(y1, y1, x1*x1))) - 2.0f*fmaf(cz, z1, fmaf(cy, y1, cx*x1));
        bool t0 = (bm[j0 >> 5] >> (j0 & 31)) & 1;
        bool t1 = (bm[j1 >> 5] >> (j1 & 31)) & 1;
        unsigned long long p0 = t0 ? PK_INF : (((unsigned long long)fmap(sq0) << 32) | (unsigned)j0);
        unsigned long long p1 = t1 ? PK_INF : (((unsigned long long)fmap(sq1) << 32) | (unsigned)j1);
        unsigned long long r = (p1 < p0) ? p1 : p0;
        unsigned long long c = (lane == owner) ? PK_INF : lpk;
        c = (r < c) ? r : c;
#pragma unroll
        for (int msk = 1; msk < 64; msk <<= 1) {
            unsigned long long ro = __shfl_xor(r, msk, 64);
            unsigned long long co = __shfl_xor(c, msk, 64);
            r = (ro < r) ? ro : r;
            c = (co < c) ? co : c;
        }
        if (lane == owner) lpk = r;
        g = c;
        __syncthreads();
    }
    if (lane < KK) idx_out[(size_t)blk*KK + lane] = (unsigned short)out_idx;
}

// ==================== transpose weights ====================
__global__ void transpose_w_kernel(const float* __restrict__ W0, const float* __restrict__ W1,
                                   const float* __restrict__ W2, float* __restrict__ w0t,
                                   float* __restrict__ w1t, float* __restrict__ w2t) {
    int t = blockIdx.x*256 + threadIdx.x;
    if (t < DD*C1)  { int c = t / C1, o = t % C1; w0t[t] = W0[o*DD + c]; }
    if (t < C1*C2)  { int c = t / C2, o = t % C2; w1t[t] = W1[o*C1 + c]; }
    if (t < C1*C3)  { int c = t / C3, o = t % C3; w2t[t] = W2[o*C1 + c]; }
}

// ==================== gram ====================
__global__ __launch_bounds__(256) void gram_kernel(const float* __restrict__ points,
                                                   const unsigned short* __restrict__ idxw,
                                                   float* __restrict__ pg) {
    __shared__ float sg[NG];
    const int tid = threadIdx.x, lane = tid & 63;
    float acc[NG];
#pragma unroll
    for (int t = 0; t < NG; ++t) acc[t] = 0.f;
#pragma unroll
    for (int i = 0; i < 4; ++i) {
        int col = blockIdx.x*1024 + i*256 + tid;
        int n = idxw[col];
        int b = col >> 15;
        const float* p = points + ((size_t)b*NN + n)*DD;
        float x[DD];
#pragma unroll
        for (int c = 0; c < DD; ++c) x[c] = p[c];
#pragma unroll
        for (int c = 0; c < DD; ++c) acc[c] += x[c];
        int t = DD;
#pragma unroll
        for (int c = 0; c < DD; ++c)
#pragma unroll
            for (int d = c; d < DD; ++d) { acc[t] = fmaf(x[c], x[d], acc[t]); ++t; }
    }
#pragma unroll
    for (int t = 0; t < NG; ++t) {
#pragma unroll
        for (int msk = 1; msk < 64; msk <<= 1) acc[t] += __shfl_xor(acc[t], msk, 64);
    }
    if (tid < NG) sg[tid] = 0.f;
    __syncthreads();
    if (lane == 0) {
#pragma unroll
        for (int t = 0; t < NG; ++t) atomicAdd(&sg[t], acc[t]);
    }
    __syncthreads();
    int bkt = blockIdx.x & (NBKT-1);
    if (tid < NG) atomicAdd(&pg[bkt*64 + tid], sg[tid]);
}

// ==================== affine1: stats1 closed-form from Gram ====================
__global__ void affine1_kernel(const float* __restrict__ pg,
                               const float* __restrict__ W0, const float* __restrict__ b0,
                               const float* __restrict__ gamma, const float* __restrict__ beta,
                               float* __restrict__ scale, float* __restrict__ shift) {
    __shared__ float sm[NG];
    int tid = threadIdx.x;
    if (tid < NG) {
        float s = 0.f;
        for (int b = 0; b < NBKT; ++b) s += pg[b*64 + tid];
        sm[tid] = s;
    }
    __syncthreads();
    if (tid < C1) {
        float w[DD];
#pragma unroll
        for (int i = 0; i < DD; ++i) w[i] = W0[tid*DD + i];
        float mv = 0.f;
#pragma unroll
        for (int i = 0; i < DD; ++i) mv = fmaf(w[i], sm[i], mv);
        float q = 0.f;
        int t = DD;
#pragma unroll
        for (int c = 0; c < DD; ++c)
#pragma unroll
            for (int d = c; d < DD; ++d) {
                float coef = w[c]*w[d];
                if (c != d) coef = coef + coef;
                q = fmaf(coef, sm[t], q); ++t;
            }
        float b0v = b0[tid];
        const float M = (float)M_COLS;
        float s_sum = mv + M*b0v;
        float s_sq  = q + 2.f*b0v*mv + M*b0v*b0v;
        const float invM = 1.0f / M;
        float mean = s_sum * invM;
        float var  = s_sq * invM - mean*mean;
        float sc   = gamma[tid] / sqrtf(var + 1e-5f);
        scale[tid] = sc;
        shift[tid] = beta[tid] - mean*sc;
    }
}

// ==================== stats helper ====================
__device__ __forceinline__ void stats_accumulate64(const float* acc,
                                                   float* __restrict__ g_sum,
                                                   float* __restrict__ g_sq) {
    __shared__ float s_sum[C1];
    __shared__ float s_sq[C1];
    int tid = threadIdx.x, lane = tid & 63;
    if (tid < C1) { s_sum[tid] = 0.f; s_sq[tid] = 0.f; }
    __syncthreads();
#pragma unroll
    for (int o = 0; o < C1; ++o) {
        float v = acc[o];
        float q = v*v;
#pragma unroll
        for (int msk = 1; msk < 64; msk <<= 1) {
            v += __shfl_xor(v, msk, 64);
            q += __shfl_xor(q, msk, 64);
        }
        if (lane == 0) { atomicAdd(&s_sum[o], v); atomicAdd(&s_sq[o], q); }
    }
    __syncthreads();
    if (tid < C1) { atomicAdd(&g_sum[tid], s_sum[tid]); atomicAdd(&g_sq[tid], s_sq[tid]); }
    __syncthreads();
}

// ==================== gather + conv1 ====================
__device__ __forceinline__ void gather_conv1(const float* __restrict__ points,
                                             const unsigned short* __restrict__ idxw,
                                             const float* __restrict__ w0t,
                                             const float* __restrict__ b0,
                                             int col, float (&a1)[C1]) {
    int n = idxw[col];
    int b = col >> 15;
    const float* p = points + ((size_t)b*NN + n)*DD;
    float x[DD];
#pragma unroll
    for (int c = 0; c < DD; ++c) x[c] = p[c];
#pragma unroll
    for (int o = 0; o < C1; ++o) a1[o] = b0[o];
#pragma unroll
    for (int c = 0; c < DD; ++c) {
        float xc = x[c];
#pragma unroll
        for (int o = 0; o < C1; ++o) a1[o] = fmaf(w0t[c*C1+o], xc, a1[o]);
    }
}

// ==================== conv2 from bn1(a1) ====================
__device__ __forceinline__ void conv2_from_a1(float (&a1)[C1],
                                              const float* __restrict__ sc1,
                                              const float* __restrict__ sh1,
                                              const float* __restrict__ w1t,
                                              const float* __restrict__ b1,
                                              float (&a2)[C2]) {
#pragma unroll
    for (int c = 0; c < C1; ++c) a1[c] = fmaxf(fmaf(a1[c], sc1[c], sh1[c]), 0.0f);
#pragma unroll
    for (int o = 0; o < C2; ++o) a2[o] = b1[o];
    for (int c = 0; c < C1; ++c) {
        float xc = a1[c];
#pragma unroll
        for (int o = 0; o < C2; ++o) a2[o] = fmaf(w1t[c*C2+o], xc, a2[o]);
    }
}

// ==================== affine (bucketed) ====================
__global__ void affine_kernel(const float* __restrict__ psum, const float* __restrict__ psq,
                              const float* __restrict__ gamma, const float* __restrict__ beta,
                              float* __restrict__ scale, float* __restrict__ shift, int nch) {
    int i = threadIdx.x;
    if (i < nch) {
        float s = 0.f, q = 0.f;
        for (int b = 0; b < NBKT; ++b) { s += psum[b*nch + i]; q += psq[b*nch + i]; }
        const float invM = 1.0f / (float)M_COLS;
        float mean = s * invM;
        float var  = q * invM - mean*mean;
        float sc   = gamma[i] / sqrtf(var + 1e-5f);
        scale[i] = sc;
        shift[i] = beta[i] - mean*sc;
    }
}

// ==================== pass2 (two variants: with/without Y2 store) ====================
template<bool STORE>
__device__ __forceinline__ void pass2_body(const float* __restrict__ points,
                                           const unsigned short* __restrict__ idxw,
                                           const float* __restrict__ w0t,
                                           const float* __restrict__ b0,
                                           const float* __restrict__ sc1,
                                           const float* __restrict__ sh1,
                                           const float* __restrict__ w1t,
                                           const float* __restrict__ b1,
                                           float* __restrict__ Y2,
                                           float* __restrict__ pstats) {
    int col = blockIdx.x*256 + threadIdx.x;
    int bkt = blockIdx.x & (NBKT-1);
    float a1[C1], a2[C2];
    gather_conv1(points, idxw, w0t, b0, col, a1);
    conv2_from_a1(a1, sc1, sh1, w1t, b1, a2);
    if (STORE) {
#pragma unroll
        for (int o = 0; o < C2; ++o) Y2[(size_t)o*M_COLS + col] = a2[o];
    }
    stats_accumulate64(a2, pstats + PS2 + bkt*C1, pstats + PQ2 + bkt*C1);
}

__global__ __launch_bounds__(256) void pass2_kernel(const float* __restrict__ points,
                                                    const unsigned short* __restrict__ idxw,
                                                    const float* __restrict__ w0t,
                                                    const float* __restrict__ b0,
                                                    const float* __restrict__ sc1,
                                                    const float* __restrict__ sh1,
                                                    const float* __restrict__ w1t,
                                                    const float* __restrict__ b1,
                                                    float* __restrict__ pstats) {
    pass2_body<false>(points, idxw, w0t, b0, sc1, sh1, w1t, b1, nullptr, pstats);
}

__global__ __launch_bounds__(256) void pass2_store_kernel(const float* __restrict__ points,
                                                          const unsigned short* __restrict__ idxw,
                                                          const float* __restrict__ w0t,
                                                          const float* __restrict__ b0,
                                                          const float* __restrict__ sc1,
                                                          const float* __restrict__ sh1,
                                                          const float* __restrict__ w1t,
                                                          const float* __restrict__ b1,
                                                          float* __restrict__ Y2,
                                                          float* __restrict__ pstats) {
    pass2_body<true>(points, idxw, w0t, b0, sc1, sh1, w1t, b1, Y2, pstats);
}

// ==================== pass34 core: bn2 -> conv3 -> pool + stats ====================
__device__ __forceinline__ void pass34_tail(float (&a2)[C2],
                                            const float* __restrict__ sc2,
                                            const float* __restrict__ sh2,
                                            const float* __restrict__ w2t,
                                            const float* __restrict__ b2,
                                            const float* __restrict__ gamma2,
                                            float* __restrict__ pool_out,
                                            float* __restrict__ pstats) {
#pragma unroll
    for (int c = 0; c < C2; ++c) a2[c] = fmaxf(fmaf(a2[c], sc2[c], sh2[c]), 0.0f);
    int col = blockIdx.x*256 + threadIdx.x;
    int bkt = blockIdx.x & (NBKT-1);
    int lane = threadIdx.x & 63;
    int bs = col >> 5;
#pragma unroll
    for (int h = 0; h < 2; ++h) {
        float acc[C1];
#pragma unroll
        for (int o = 0; o < C1; ++o) acc[o] = b2[h*C1+o];
        for (int c = 0; c < C2; ++c) {
            float xc = a2[c];
#pragma unroll
            for (int o = 0; o < C1; ++o) acc[o] = fmaf(w2t[c*C3 + h*C1 + o], xc, acc[o]);
        }
#pragma unroll
        for (int o = 0; o < C1; ++o) {
            bool pos = gamma2[h*C1+o] >= 0.f;
            float v = pos ? acc[o] : -acc[o];
#pragma unroll
            for (int msk = 1; msk < 32; msk <<= 1) v = fmaxf(v, __shfl_xor(v, msk, 64));
            if ((lane & 31) == 0) pool_out[(size_t)bs*C3 + h*C1 + o] = pos ? v : -v;
        }
        stats_accumulate64(acc, pstats + PS3 + bkt*C3 + h*C1, pstats + PQ3 + bkt*C3 + h*C1);
    }
}

__global__ __launch_bounds__(256) void pass34_kernel(const float* __restrict__ points,
                                                     const unsigned short* __restrict__ idxw,
                                                     const float* __restrict__ w0t,
                                                     const float* __restrict__ b0,
                                                     const float* __restrict__ sc1,
                                                     const float* __restrict__ sh1,
                                                     const float* __restrict__ w1t,
                                                     const float* __restrict__ b1,
                                                     const float* __restrict__ sc2,
                                                     const float* __restrict__ sh2,
                                                     const float* __restrict__ w2t,
                                                     const float* __restrict__ b2,
                                                     const float* __restrict__ gamma2,
                                                     float* __restrict__ pool_out,
                                                     float* __restrict__ pstats) {
    int col = blockIdx.x*256 + threadIdx.x;
    float a1[C1], a2[C2];
    gather_conv1(points, idxw, w0t, b0, col, a1);
    conv2_from_a1(a1, sc1, sh1, w1t, b1, a2);
    pass34_tail(a2, sc2, sh2, w2t, b2, gamma2, pool_out, pstats);
}

__global__ __launch_bounds__(256) void pass34_cached_kernel(const float* __restrict__ Y2,
                                                            const float* __restrict__ sc2,
                                                            const float* __restrict__ sh2,
                                                            const float* __restrict__ w2t,
                                                            const float* __restrict__ b2,
                                                            const float* __restrict__ gamma2,
                                                            float* __restrict__ pool_out,
                                                            float* __restrict__ pstats) {
    int col = blockIdx.x*256 + threadIdx.x;
    float a2[C2];
#pragma unroll
    for (int o = 0; o < C2; ++o) a2[o] = Y2[(size_t)o*M_COLS + col];
    pass34_tail(a2, sc2, sh2, w2t, b2, gamma2, pool_out, pstats);
}

// ==================== epilogue: bn3 + relu ====================
__global__ __launch_bounds__(256) void bn3relu_kernel(float* __restrict__ pool,
                                                      const float* __restrict__ sc3,
                                                      const float* __restrict__ sh3) {
    int e = blockIdx.x*256 + threadIdx.x;
    int ch = e & (C3-1);
    float v = pool[e];
    pool[e] = fmaxf(fmaf(v, sc3[ch], sh3[ch]), 0.0f);
}

extern "C" void kernel_launch(void* const* d_in, const int* in_sizes, int n_in,
                              void* d_out, int out_size, void* d_ws, size_t ws_size,
                              hipStream_t stream) {
    const float* xyz    = (const float*)d_in[0];
    const float* points = (const float*)d_in[1];
    const float* W0     = (const float*)d_in[2];
    const float* b0     = (const float*)d_in[3];
    const float* gamma0 = (const float*)d_in[4];
    const float* beta0  = (const float*)d_in[5];
    const float* W1     = (const float*)d_in[6];
    const float* b1     = (const float*)d_in[7];
    const float* gamma1 = (const float*)d_in[8];
    const float* beta1  = (const float*)d_in[9];
    const float* W2     = (const float*)d_in[10];
    const float* b2     = (const float*)d_in[11];
    const float* gamma2 = (const float*)d_in[12];
    const float* beta2  = (const float*)d_in[13];

    char* wsb = (char*)d_ws;
    unsigned short* idxw = (unsigned short*)(wsb + WSB_IDX);
    float* pstats = (float*)(wsb + WSB_STATS);
    float* aff = (float*)(wsb + WSB_AFF);
    float* sc1 = aff,       *sh1 = aff + 64;
    float* sc2 = aff + 128, *sh2 = aff + 192;
    float* sc3 = aff + 256, *sh3 = aff + 384;
    float* wT  = (float*)(wsb + WSB_WT);
    float* w0t = wT, *w1t = wT + DD*C1, *w2t = wT + DD*C1 + C1*C2;
    float* Y2  = (float*)(wsb + WSB_Y2);
    const bool use_y2 = ws_size >= (size_t)WSB_Y2 + (size_t)C2 * M_COLS * 4;

    float* out_newxyz = (float*)d_out;
    float* out_feat   = (float*)d_out + (size_t)BB*SS*3;

    hipMemsetAsync(pstats, 0, 32768*sizeof(float), stream);
    fps_kernel<<<dim3(BB), dim3(FPS_T), 0, stream>>>(xyz, out_newxyz);
    transpose_w_kernel<<<dim3(32), dim3(256), 0, stream>>>(W0, W1, W2, w0t, w1t, w2t);
    query_kernel<<<dim3(BB*SS), dim3(64), 0, stream>>>(xyz, out_newxyz, idxw);
    gram_kernel<<<dim3(M_COLS/1024), dim3(256), 0, stream>>>(points, idxw, pstats + PG1);
    affine1_kernel<<<dim3(1), dim3(64), 0, stream>>>(pstats + PG1, W0, b0, gamma0, beta0, sc1, sh1);
    if (use_y2) {
        pass2_store_kernel<<<dim3(M_COLS/256), dim3(256), 0, stream>>>(points, idxw, w0t, b0, sc1, sh1, w1t, b1, Y2, pstats);
        affine_kernel<<<dim3(1), dim3(128), 0, stream>>>(pstats + PS2, pstats + PQ2, gamma1, beta1, sc2, sh2, C2);
        pass34_cached_kernel<<<dim3(M_COLS/256), dim3(256), 0, stream>>>(Y2, sc2, sh2, w2t, b2, gamma2, out_feat, pstats);
    } else {
        pass2_kernel<<<dim3(M_COLS/256), dim3(256), 0, stream>>>(points, idxw, w0t, b0, sc1, sh1, w1t, b1, pstats);
        affine_kernel<<<dim3(1), dim3(128), 0, stream>>>(pstats + PS2, pstats + PQ2, gamma1, beta1, sc2, sh2, C2);
        pass34_kernel<<<dim3(M_COLS/256), dim3(256), 0, stream>>>(points, idxw, w0t, b0, sc1, sh1, w1t, b1, sc2, sh2, w2t, b2, gamma2, out_feat, pstats);
    }
    affine_kernel<<<dim3(1), dim3(128), 0, stream>>>(pstats + PS3, pstats + PQ3, gamma2, beta2, sc3, sh3, C3);
    bn3relu_kernel<<<dim3((BB*SS*C3)/256), dim3(256), 0, stream>>>(out_feat, sc3, sh3);
}